// Round 2
// baseline (338.613 us; speedup 1.0000x reference)
//
#include <hip/hip_runtime.h>
#include <stdint.h>

#define DEVI static __device__ __forceinline__

typedef unsigned short u16;
typedef unsigned int u32;
typedef __attribute__((ext_vector_type(8))) short short8;
typedef __attribute__((ext_vector_type(4))) float f32x4;
typedef __attribute__((ext_vector_type(4))) unsigned short ushort4_t;

#define BB 4
#define SS 4096
#define DD 1024
#define HH 16
#define HDD 64
#define MM 256
#define BHN 64

DEVI u16 f2bf(float f) {
    u32 u = __float_as_uint(f);
    u += 0x7fffu + ((u >> 16) & 1u);
    return (u16)(u >> 16);
}
DEVI float bf2f(u16 h) { return __uint_as_float(((u32)h) << 16); }
DEVI float bsq(u32 u) {
    float lo = __uint_as_float(u << 16);
    float hi = __uint_as_float(u & 0xffff0000u);
    return lo * lo + hi * hi;
}
DEVI u32 fenc(float f) {
    u32 u = __float_as_uint(f);
    return (u & 0x80000000u) ? ~u : (u | 0x80000000u);
}
DEVI float fdec(u32 k) {
    u32 u = (k & 0x80000000u) ? (k & 0x7fffffffu) : ~k;
    return __uint_as_float(u);
}

typedef __attribute__((address_space(1))) const unsigned int as1_u32;
typedef __attribute__((address_space(3))) unsigned int as3_u32;
DEVI void load_lds16(const void* g, void* lds) {
    __builtin_amdgcn_global_load_lds((as1_u32*)g, (as3_u32*)lds, 16, 0, 0);
}

// ---------------- conversion kernels ----------------

__global__ void conv_bf16(const float* __restrict__ src, u16* __restrict__ dst, int n4) {
    int i = blockIdx.x * 256 + threadIdx.x;
    if (i < n4) {
        float4 v = reinterpret_cast<const float4*>(src)[i];
        ushort4_t o = { f2bf(v.x), f2bf(v.y), f2bf(v.z), f2bf(v.w) };
        reinterpret_cast<ushort4_t*>(dst)[i] = o;
    }
}

__global__ void conv_w(const float* __restrict__ Wq, const float* __restrict__ Wk,
                       const float* __restrict__ Wv, u16* __restrict__ Wt) {
    __shared__ float tile[64][65];
    const int jt = blockIdx.x, kt = blockIdx.y;
    const float* src = (jt < 16) ? Wq : (jt < 32) ? Wk : Wv;
    const int j0 = (jt & 15) * 64, k0 = kt * 64;
    const int t = threadIdx.x;
    for (int i = 0; i < 16; ++i) {
        int lin = t + i * 256;
        int kl = lin >> 6, jl = lin & 63;
        tile[kl][jl] = src[(size_t)(k0 + kl) * DD + j0 + jl];
    }
    __syncthreads();
    const int jg0 = jt * 64;
    for (int i = 0; i < 16; ++i) {
        int lin = t + i * 256;
        int jl = lin >> 6, kl = lin & 63;
        Wt[(size_t)(jg0 + jl) * DD + k0 + kl] = f2bf(tile[kl][jl]);
    }
}

// ---------------- QKV projection GEMM (m97-structure) ----------------
__global__ __launch_bounds__(256, 2) void gemm1(
    const u16* __restrict__ Xbf, const u16* __restrict__ Wt,
    const float* __restrict__ bq, const float* __restrict__ bk, const float* __restrict__ bv,
    const float* __restrict__ mask,
    u16* __restrict__ Qh, u16* __restrict__ Kh, u16* __restrict__ Vt)
{
    __shared__ __align__(16) u16 Alds[128 * 32];
    __shared__ __align__(16) u16 Blds[128 * 32];
    const int tid = threadIdx.x;
    const int l = tid & 63, wv = tid >> 6;
    const int wr = wv >> 1, wc = wv & 1;
    const int row0 = blockIdx.x * 128;
    const int j0 = blockIdx.y * 128;
    f32x4 acc[4][4] = {};
    const int lr = l >> 2;
    const int lo = (l & 3) * 8;
    for (int kt = 0; kt < 32; ++kt) {
        const int kb = kt * 32;
#pragma unroll
        for (int c = 0; c < 2; ++c) {
            const int rbase = wv * 32 + c * 16;
            load_lds16(Xbf + (size_t)(row0 + rbase + lr) * DD + kb + lo, (char*)Alds + rbase * 64);
            load_lds16(Wt + (size_t)(j0 + rbase + lr) * DD + kb + lo, (char*)Blds + rbase * 64);
        }
        __syncthreads();
        short8 af[4], bfr[4];
#pragma unroll
        for (int mf = 0; mf < 4; ++mf)
            af[mf] = *(const short8*)((const char*)Alds + (wr * 64 + mf * 16 + (l & 15)) * 64 + (l >> 4) * 16);
#pragma unroll
        for (int nf = 0; nf < 4; ++nf)
            bfr[nf] = *(const short8*)((const char*)Blds + (wc * 64 + nf * 16 + (l & 15)) * 64 + (l >> 4) * 16);
#pragma unroll
        for (int mf = 0; mf < 4; ++mf)
#pragma unroll
            for (int nf = 0; nf < 4; ++nf)
                acc[mf][nf] = __builtin_amdgcn_mfma_f32_16x16x32_bf16(af[mf], bfr[nf], acc[mf][nf], 0, 0, 0);
        __syncthreads();
    }
    const int region = j0 >> 10;
    const int jj0 = j0 & 1023;
#pragma unroll
    for (int mf = 0; mf < 4; ++mf) {
        const int rloc = wr * 64 + mf * 16 + (l >> 4) * 4;
        const int r = row0 + rloc;
        const int b = r >> 12, s = r & 4095;
#pragma unroll
        for (int nf = 0; nf < 4; ++nf) {
            const int cloc = wc * 64 + nf * 16 + (l & 15);
            const int j = jj0 + cloc;
            const int h = j >> 6, d = j & 63;
            if (region == 0) {
                const float bias = bq[j];
#pragma unroll
                for (int g = 0; g < 4; ++g)
                    Qh[((size_t)(b * HH + h) * SS + s + g) * HDD + d] = f2bf((acc[mf][nf][g] + bias) * 0.125f);
            } else if (region == 1) {
                const float bias = bk[j];
#pragma unroll
                for (int g = 0; g < 4; ++g) {
                    const float m = mask[b * SS + s + g];
                    Kh[((size_t)(b * HH + h) * SS + s + g) * HDD + d] = f2bf((acc[mf][nf][g] + bias) * m * 0.125f);
                }
            } else {
                const float bias = bv[j];
                ushort4_t pk;
#pragma unroll
                for (int g = 0; g < 4; ++g) {
                    const float m = mask[b * SS + s + g];
                    pk[g] = f2bf((acc[mf][nf][g] + bias) * m);
                }
                *(ushort4_t*)(Vt + ((size_t)(b * HH + h) * HDD + d) * SS + s) = pk;
            }
        }
    }
}

// ---------------- diag = 0.5*|x|^2 per row ----------------
__global__ void diag_kernel(const u16* __restrict__ Qh, const u16* __restrict__ Kh,
                            float* __restrict__ dq, float* __restrict__ dk) {
    const size_t r = (size_t)blockIdx.x * 256 + threadIdx.x;
    const uint4* pq = (const uint4*)(Qh + r * HDD);
    const uint4* pk = (const uint4*)(Kh + r * HDD);
    float sq = 0.f, sk = 0.f;
#pragma unroll
    for (int i = 0; i < 8; ++i) {
        uint4 a = pq[i], b = pk[i];
        sq += bsq(a.x) + bsq(a.y) + bsq(a.z) + bsq(a.w);
        sk += bsq(b.x) + bsq(b.y) + bsq(b.z) + bsq(b.w);
    }
    dq[r] = 0.5f * sq;
    dk[r] = 0.5f * sk;
}

// ---------------- stab: global max of u_k per (b,h) ----------------
__global__ __launch_bounds__(256, 2) void stab_kernel(
    const u16* __restrict__ Kh, const u16* __restrict__ projb, u32* __restrict__ stabkey)
{
    __shared__ __align__(16) u16 Klds[64 * 64];
    __shared__ float red4[4];
    const int tid = threadIdx.x, l = tid & 63, wv = tid >> 6;
    const int rt = blockIdx.x, bh = blockIdx.y;
    // proj B-frags: col m = wv*64 + nf*16 + (l&15), k = d
    short8 pb[4][2];
#pragma unroll
    for (int nf = 0; nf < 4; ++nf)
#pragma unroll
        for (int ks = 0; ks < 2; ++ks)
            pb[nf][ks] = *(const short8*)(projb + (wv * 64 + nf * 16 + (l & 15)) * HDD + ks * 32 + (l >> 4) * 8);
    const size_t sbase = (size_t)bh * SS + rt * 64;
#pragma unroll
    for (int c = 0; c < 2; ++c) {
        const int rb = wv * 16 + c * 8;
        const int r = rb + (l >> 3);
        load_lds16(Kh + (sbase + r) * HDD + (((l & 7) ^ (r & 7)) * 8), (char*)Klds + rb * 128);
    }
    __syncthreads();
    float mx = -3.0e38f;
#pragma unroll
    for (int sf = 0; sf < 4; ++sf) {
        const int s = sf * 16 + (l & 15);
        f32x4 u4[4] = {};
#pragma unroll
        for (int ks = 0; ks < 2; ++ks) {
            short8 ak = *(const short8*)((const char*)Klds + s * 128 + ((ks * 64 + (l >> 4) * 16) ^ ((s & 7) << 4)));
#pragma unroll
            for (int nf = 0; nf < 4; ++nf)
                u4[nf] = __builtin_amdgcn_mfma_f32_16x16x32_bf16(ak, pb[nf][ks], u4[nf], 0, 0, 0);
        }
#pragma unroll
        for (int nf = 0; nf < 4; ++nf)
#pragma unroll
            for (int g = 0; g < 4; ++g) mx = fmaxf(mx, u4[nf][g]);
    }
#pragma unroll
    for (int o = 1; o < 64; o <<= 1) mx = fmaxf(mx, __shfl_xor(mx, o));
    if (l == 0) red4[wv] = mx;
    __syncthreads();
    if (tid == 0) {
        float m2 = fmaxf(fmaxf(red4[0], red4[1]), fmaxf(red4[2], red4[3]));
        atomicMax(stabkey + bh, fenc(m2));
    }
}

// ---------------- kv_fused: k' on the fly, kv = k'^T Vs + ksum ----------------
__global__ __launch_bounds__(256, 2) void kv_fused(
    const u16* __restrict__ Kh, const u16* __restrict__ Vt,
    const u16* __restrict__ projb, const float* __restrict__ dk,
    const u32* __restrict__ stabkey,
    float* __restrict__ kv_part, float* __restrict__ ksum_part)
{
    __shared__ __align__(16) u16 Klds[64 * 64];
    __shared__ __align__(16) u16 Vlds[64 * 64];
    __shared__ __align__(16) u16 Kp[256 * 64];   // k' tile [m][s], swizzled
    const int tid = threadIdx.x, l = tid & 63, wv = tid >> 6;
    const int ck = blockIdx.x, bh = blockIdx.y;
    const float stab = fdec(stabkey[bh]);
    short8 pb[4][2];
#pragma unroll
    for (int nf = 0; nf < 4; ++nf)
#pragma unroll
        for (int ks = 0; ks < 2; ++ks)
            pb[nf][ks] = *(const short8*)(projb + (wv * 64 + nf * 16 + (l & 15)) * HDD + ks * 32 + (l >> 4) * 8);
    f32x4 acc[4][4] = {};
    float ksc[4] = {0.f, 0.f, 0.f, 0.f};
    const size_t sbase = (size_t)bh * SS + ck * 512;
    for (int it = 0; it < 8; ++it) {
        const int s0 = it * 64;
#pragma unroll
        for (int c = 0; c < 2; ++c) {
            const int rb = wv * 16 + c * 8;
            const int r = rb + (l >> 3);
            const int sc = ((l & 7) ^ (r & 7)) * 8;
            load_lds16(Kh + (sbase + s0 + r) * HDD + sc, (char*)Klds + rb * 128);
            load_lds16(Vt + ((size_t)bh * HDD + r) * SS + ck * 512 + s0 + sc, (char*)Vlds + rb * 128);
        }
        __syncthreads();
        // u^T: A = Kh rows s, B = proj rows m -> D row=s(g-consecutive), col=m
#pragma unroll
        for (int sf = 0; sf < 4; ++sf) {
            const int s = sf * 16 + (l & 15);
            f32x4 u4[4] = {};
#pragma unroll
            for (int ks = 0; ks < 2; ++ks) {
                short8 ak = *(const short8*)((const char*)Klds + s * 128 + ((ks * 64 + (l >> 4) * 16) ^ ((s & 7) << 4)));
#pragma unroll
                for (int nf = 0; nf < 4; ++nf)
                    u4[nf] = __builtin_amdgcn_mfma_f32_16x16x32_bf16(ak, pb[nf][ks], u4[nf], 0, 0, 0);
            }
            const int srow = sf * 16 + (l >> 4) * 4;   // D-row base (g=0..3)
            const float4 dkv = *(const float4*)(dk + sbase + s0 + srow);
#pragma unroll
            for (int nf = 0; nf < 4; ++nf) {
                const int m = wv * 64 + nf * 16 + (l & 15);
                u16 h0 = f2bf(0.0625f * (__expf(u4[nf][0] - dkv.x - stab) + 1e-4f));
                u16 h1 = f2bf(0.0625f * (__expf(u4[nf][1] - dkv.y - stab) + 1e-4f));
                u16 h2 = f2bf(0.0625f * (__expf(u4[nf][2] - dkv.z - stab) + 1e-4f));
                u16 h3 = f2bf(0.0625f * (__expf(u4[nf][3] - dkv.w - stab) + 1e-4f));
                ksc[nf] += bf2f(h0) + bf2f(h1) + bf2f(h2) + bf2f(h3);
                uint2 w; w.x = (u32)h0 | ((u32)h1 << 16); w.y = (u32)h2 | ((u32)h3 << 16);
                *(uint2*)((char*)Kp + m * 128 + ((srow * 2) ^ ((m & 7) << 4))) = w;
            }
        }
        // kv: A = k' rows m (own wave slice), B = V rows d
#pragma unroll
        for (int ks = 0; ks < 2; ++ks) {
            short8 am[4], bv8[4];
#pragma unroll
            for (int mf = 0; mf < 4; ++mf) {
                const int m = wv * 64 + mf * 16 + (l & 15);
                am[mf] = *(const short8*)((const char*)Kp + m * 128 + ((ks * 64 + (l >> 4) * 16) ^ ((m & 7) << 4)));
            }
#pragma unroll
            for (int nf = 0; nf < 4; ++nf) {
                const int d = nf * 16 + (l & 15);
                bv8[nf] = *(const short8*)((const char*)Vlds + d * 128 + ((ks * 64 + (l >> 4) * 16) ^ ((d & 7) << 4)));
            }
#pragma unroll
            for (int mf = 0; mf < 4; ++mf)
#pragma unroll
                for (int nf = 0; nf < 4; ++nf)
                    acc[mf][nf] = __builtin_amdgcn_mfma_f32_16x16x32_bf16(am[mf], bv8[nf], acc[mf][nf], 0, 0, 0);
        }
        __syncthreads();
    }
    const size_t pbase = (size_t)ck * BHN + bh;
#pragma unroll
    for (int nf = 0; nf < 4; ++nf) {
        float v = ksc[nf];
        v += __shfl_xor(v, 16);
        v += __shfl_xor(v, 32);
        if (l < 16) ksum_part[pbase * MM + wv * 64 + nf * 16 + l] = v;
    }
#pragma unroll
    for (int mf = 0; mf < 4; ++mf)
#pragma unroll
        for (int nf = 0; nf < 4; ++nf)
            *(f32x4*)(kv_part + (pbase * HDD + nf * 16 + (l & 15)) * MM + wv * 64 + mf * 16 + (l >> 4) * 4) = acc[mf][nf];
}

// ---------------- reduce partials -> Bmat[bh][80][256] bf16 ----------------
__global__ void reduceB(const float* __restrict__ kv_part, const float* __restrict__ ksum_part,
                        u16* __restrict__ Bmat) {
    const int bh = blockIdx.x, t = threadIdx.x;
    for (int n = 0; n < 64; ++n) {
        float s = 0.f;
#pragma unroll
        for (int ck = 0; ck < 8; ++ck) s += kv_part[(((size_t)ck * BHN + bh) * HDD + n) * MM + t];
        Bmat[((size_t)bh * 80 + n) * MM + t] = f2bf(s);
    }
    float s = 0.f;
#pragma unroll
    for (int ck = 0; ck < 8; ++ck) s += ksum_part[((size_t)ck * BHN + bh) * MM + t];
    Bmat[((size_t)bh * 80 + 64) * MM + t] = f2bf(s);
    for (int n = 65; n < 80; ++n) Bmat[((size_t)bh * 80 + n) * MM + t] = 0;
}

// ---------------- out_fused: q' on the fly, out = (q' @ [kv|ksum]) * z ----------------
__global__ __launch_bounds__(256, 2) void out_fused(
    const u16* __restrict__ Qh, const u16* __restrict__ projb,
    const float* __restrict__ dq, const u16* __restrict__ Bmat,
    float* __restrict__ out)
{
    __shared__ __align__(16) u16 Blds[80 * 256];   // rows n, 512B stride, swizzled
    __shared__ __align__(16) u16 Qlds[32 * 64];
    __shared__ __align__(16) u16 qlds[32 * 256];   // q' [s][m], swizzled
    __shared__ float red[4][32];
    const int tid = threadIdx.x, l = tid & 63, wv = tid >> 6;
    const int rt = blockIdx.x, bh = blockIdx.y;
#pragma unroll
    for (int c = 0; c < 10; ++c) {
        const int r = (wv * 10 + c) * 2 + (l >> 5);
        load_lds16(Bmat + (size_t)bh * 20480 + r * 256 + (((l & 31) ^ (r & 7)) * 8),
                   (char*)Blds + (wv * 10 + c) * 1024);
    }
    const size_t srowbase = (size_t)bh * SS + rt * 32;
    {
        const int rb = wv * 8;
        const int r = rb + (l >> 3);
        load_lds16(Qh + (srowbase + r) * HDD + (((l & 7) ^ (r & 7)) * 8), (char*)Qlds + rb * 128);
    }
    // proj A-frags: rows m = wv*64 + mf*16 + (l&15)
    short8 pa[4][2];
#pragma unroll
    for (int mf = 0; mf < 4; ++mf)
#pragma unroll
        for (int ks = 0; ks < 2; ++ks)
            pa[mf][ks] = *(const short8*)(projb + (wv * 64 + mf * 16 + (l & 15)) * HDD + ks * 32 + (l >> 4) * 8);
    __syncthreads();
    // u: A = proj m (g-consecutive rows), B = Qh s; D row=m, col=s
    f32x4 u[4][2] = {};
#pragma unroll
    for (int ks = 0; ks < 2; ++ks) {
        short8 bq8[2];
#pragma unroll
        for (int nf = 0; nf < 2; ++nf) {
            const int s = nf * 16 + (l & 15);
            bq8[nf] = *(const short8*)((const char*)Qlds + s * 128 + ((ks * 64 + (l >> 4) * 16) ^ ((s & 7) << 4)));
        }
#pragma unroll
        for (int mf = 0; mf < 4; ++mf)
#pragma unroll
            for (int nf = 0; nf < 2; ++nf)
                u[mf][nf] = __builtin_amdgcn_mfma_f32_16x16x32_bf16(pa[mf][ks], bq8[nf], u[mf][nf], 0, 0, 0);
    }
    // rowmax over this wave's 64 m per s-col
#pragma unroll
    for (int nf = 0; nf < 2; ++nf) {
        float v = -3.0e38f;
#pragma unroll
        for (int mf = 0; mf < 4; ++mf)
#pragma unroll
            for (int g = 0; g < 4; ++g) v = fmaxf(v, u[mf][nf][g]);
        v = fmaxf(v, __shfl_xor(v, 16));
        v = fmaxf(v, __shfl_xor(v, 32));
        if ((l >> 4) == 0) red[wv][nf * 16 + l] = v;
    }
    __syncthreads();
    // q' -> qlds
#pragma unroll
    for (int nf = 0; nf < 2; ++nf) {
        const int s = nf * 16 + (l & 15);
        const float mx = fmaxf(fmaxf(red[0][s], red[1][s]), fmaxf(red[2][s], red[3][s]));
        const float dg = dq[srowbase + s];
#pragma unroll
        for (int mf = 0; mf < 4; ++mf) {
            u16 h0 = f2bf(0.0625f * (__expf(u[mf][nf][0] - dg - mx) + 1e-4f));
            u16 h1 = f2bf(0.0625f * (__expf(u[mf][nf][1] - dg - mx) + 1e-4f));
            u16 h2 = f2bf(0.0625f * (__expf(u[mf][nf][2] - dg - mx) + 1e-4f));
            u16 h3 = f2bf(0.0625f * (__expf(u[mf][nf][3] - dg - mx) + 1e-4f));
            uint2 w; w.x = (u32)h0 | ((u32)h1 << 16); w.y = (u32)h2 | ((u32)h3 << 16);
            const int mb = (wv * 64 + mf * 16 + (l >> 4) * 4) * 2;
            *(uint2*)((char*)qlds + s * 512 + (mb ^ ((s & 7) << 4))) = w;
        }
    }
    __syncthreads();
    // out GEMM: A = q' rows s (mf 0..1), B = Blds rows {wv*16.., 64..79}
    f32x4 acc[2][2] = {};
    for (int kt = 0; kt < 8; ++kt) {
        short8 aq[2], bb[2];
#pragma unroll
        for (int mf = 0; mf < 2; ++mf) {
            const int s = mf * 16 + (l & 15);
            aq[mf] = *(const short8*)((const char*)qlds + s * 512 + ((kt * 64 + (l >> 4) * 16) ^ ((s & 7) << 4)));
        }
        {
            const int n0 = wv * 16 + (l & 15);
            bb[0] = *(const short8*)((const char*)Blds + n0 * 512 + ((kt * 64 + (l >> 4) * 16) ^ ((n0 & 7) << 4)));
            const int n1 = 64 + (l & 15);
            bb[1] = *(const short8*)((const char*)Blds + n1 * 512 + ((kt * 64 + (l >> 4) * 16) ^ ((n1 & 7) << 4)));
        }
#pragma unroll
        for (int mf = 0; mf < 2; ++mf)
#pragma unroll
            for (int nf = 0; nf < 2; ++nf)
                acc[mf][nf] = __builtin_amdgcn_mfma_f32_16x16x32_bf16(aq[mf], bb[nf], acc[mf][nf], 0, 0, 0);
    }
    const int b = bh >> 4, h = bh & 15;
#pragma unroll
    for (int mf = 0; mf < 2; ++mf) {
#pragma unroll
        for (int g = 0; g < 4; ++g) {
            const float den = __shfl(acc[mf][1][g], (l & 48));
            const float z = 1.0f / (den + 1e-6f);
            const int s = rt * 32 + mf * 16 + (l >> 4) * 4 + g;
            out[((size_t)b * SS + s) * DD + h * HDD + wv * 16 + (l & 15)] = acc[mf][0][g] * z;
        }
    }
}

// ---------------- launcher ----------------
extern "C" void kernel_launch(void* const* d_in, const int* in_sizes, int n_in,
                              void* d_out, int out_size, void* d_ws, size_t ws_size,
                              hipStream_t stream)
{
    const float* X    = (const float*)d_in[0];
    const float* mask = (const float*)d_in[1];
    const float* Wq   = (const float*)d_in[2];
    const float* bq   = (const float*)d_in[3];
    const float* Wk   = (const float*)d_in[4];
    const float* bk   = (const float*)d_in[5];
    const float* Wv   = (const float*)d_in[6];
    const float* bv   = (const float*)d_in[7];
    const float* proj = (const float*)d_in[8];
    float* out = (float*)d_out;

    char* p = (char*)d_ws;
    u16* Xbf = (u16*)p;                            // 32 MB (aliased by kv_part after gemm1)
    float* kv_part = (float*)p; p += 33554432;     // [8][bh][d][m] fp32
    u16* Wt = (u16*)p;    p += 6291456;            // 3072x1024 bf16
    u16* projb = (u16*)p; p += 32768;              // 256x64 bf16
    u16* Qh = (u16*)p;    p += 33554432;           // [bh][s][d] = Q/8
    u16* Kh = (u16*)p;    p += 33554432;           // [bh][s][d] = K*mask/8
    u16* Vt = (u16*)p;    p += 33554432;           // [bh][d][s] = V*mask
    float* dq = (float*)p; p += 1048576;
    float* dk = (float*)p; p += 1048576;
    u32* stabkey = (u32*)p; p += 256;
    float* ksum_part = (float*)p; p += 524288;     // [8][bh][m]
    u16* Bmat = (u16*)p;  p += 2621440;            // [bh][80][256]
    // total = 145,785,088 bytes
    if (ws_size < 145785088ull) return;  // diagnostic: absmax-fail instead of crash

    hipMemsetAsync(stabkey, 0, 256, stream);
    conv_bf16<<<16384, 256, 0, stream>>>(X, Xbf, 4194304);
    conv_w<<<dim3(48, 16), 256, 0, stream>>>(Wq, Wk, Wv, Wt);
    conv_bf16<<<16, 256, 0, stream>>>(proj, projb, 4096);
    gemm1<<<dim3(128, 24), 256, 0, stream>>>(Xbf, Wt, bq, bk, bv, mask, Qh, Kh, Vt);
    diag_kernel<<<1024, 256, 0, stream>>>(Qh, Kh, dq, dk);
    stab_kernel<<<dim3(64, 64), 256, 0, stream>>>(Kh, projb, stabkey);
    kv_fused<<<dim3(8, 64), 256, 0, stream>>>(Kh, Vt, projb, dk, stabkey, kv_part, ksum_part);
    reduceB<<<64, 256, 0, stream>>>(kv_part, ksum_part, Bmat);
    out_fused<<<dim3(128, 64), 256, 0, stream>>>(Qh, projb, dq, Bmat, out);
}

// Round 3
// 323.015 us; speedup vs baseline: 1.0483x; 1.0483x over previous
//
#include <hip/hip_runtime.h>
#include <stdint.h>

#define DEVI static __device__ __forceinline__

typedef unsigned short u16;
typedef unsigned int u32;
typedef __attribute__((ext_vector_type(8))) short short8;
typedef __attribute__((ext_vector_type(4))) float f32x4;
typedef __attribute__((ext_vector_type(4))) unsigned short ushort4_t;

#define BB 4
#define SS 4096
#define DD 1024
#define HH 16
#define HDD 64
#define MM 256
#define BHN 64

DEVI u16 f2bf(float f) {
    u32 u = __float_as_uint(f);
    u += 0x7fffu + ((u >> 16) & 1u);
    return (u16)(u >> 16);
}
DEVI float bf2f(u16 h) { return __uint_as_float(((u32)h) << 16); }
DEVI float bsq(u32 u) {
    float lo = __uint_as_float(u << 16);
    float hi = __uint_as_float(u & 0xffff0000u);
    return lo * lo + hi * hi;
}
DEVI u32 fenc(float f) {
    u32 u = __float_as_uint(f);
    return (u & 0x80000000u) ? ~u : (u | 0x80000000u);
}
DEVI float fdec(u32 k) {
    u32 u = (k & 0x80000000u) ? (k & 0x7fffffffu) : ~k;
    return __uint_as_float(u);
}

typedef __attribute__((address_space(1))) const unsigned int as1_u32;
typedef __attribute__((address_space(3))) unsigned int as3_u32;
DEVI void load_lds16(const void* g, void* lds) {
    __builtin_amdgcn_global_load_lds((as1_u32*)g, (as3_u32*)lds, 16, 0, 0);
}

// ---------------- conversion kernels ----------------

__global__ void conv_bf16(const float* __restrict__ src, u16* __restrict__ dst, int n4) {
    int i = blockIdx.x * 256 + threadIdx.x;
    if (i < n4) {
        float4 v = reinterpret_cast<const float4*>(src)[i];
        ushort4_t o = { f2bf(v.x), f2bf(v.y), f2bf(v.z), f2bf(v.w) };
        reinterpret_cast<ushort4_t*>(dst)[i] = o;
    }
}

__global__ void conv_w(const float* __restrict__ Wq, const float* __restrict__ Wk,
                       const float* __restrict__ Wv, u16* __restrict__ Wt) {
    __shared__ float tile[64][65];
    const int jt = blockIdx.x, kt = blockIdx.y;
    const float* src = (jt < 16) ? Wq : (jt < 32) ? Wk : Wv;
    const int j0 = (jt & 15) * 64, k0 = kt * 64;
    const int t = threadIdx.x;
    for (int i = 0; i < 16; ++i) {
        int lin = t + i * 256;
        int kl = lin >> 6, jl = lin & 63;
        tile[kl][jl] = src[(size_t)(k0 + kl) * DD + j0 + jl];
    }
    __syncthreads();
    const int jg0 = jt * 64;
    for (int i = 0; i < 16; ++i) {
        int lin = t + i * 256;
        int jl = lin >> 6, kl = lin & 63;
        Wt[(size_t)(jg0 + jl) * DD + k0 + kl] = f2bf(tile[kl][jl]);
    }
}

// ---------------- QKV projection GEMM: 3-buffer deep pipeline ----------------
// BM=128, BN=256, BK=64; 512 thr = 8 waves (2M x 4N); per-wave 64x64 out.
// LDS: 3 x (A 16KB + B 32KB) = 144KB dynamic. Counted vmcnt(6) at boundaries.
// Fused epilogue: scatter Q/K/V + diag_q/diag_k.
__global__ __launch_bounds__(512) void gemm1_8ph(
    const u16* __restrict__ Xbf, const u16* __restrict__ Wt,
    const float* __restrict__ bq, const float* __restrict__ bk, const float* __restrict__ bv,
    const float* __restrict__ mask,
    u16* __restrict__ Qh, u16* __restrict__ Kh, u16* __restrict__ Vt,
    float* __restrict__ dq, float* __restrict__ dk)
{
    extern __shared__ __align__(16) char smem[];
    const int tid = threadIdx.x, l = tid & 63, wv = tid >> 6;
    const int wm = wv >> 2, wn = wv & 3;
    const int flat = blockIdx.x;
    const int swz = (flat & 7) * 192 + (flat >> 3);   // 1536 = 8*192, bijective
    const int bx = swz / 12, by = swz % 12;
    const int row0 = bx * 128, col0 = by * 256;

    const int srow = tid >> 3;                        // 0..63 within a round
    const int scol = ((tid & 7) ^ (srow & 7)) * 8;    // pre-swizzled source col (elems)

    // LDS tile bases
    #define ABUF(p) ((char*)smem + (p) * 16384)
    #define BBUF(p) ((char*)smem + 49152 + (p) * 32768)

    // stage one 8KB round: A round r covers rows r*64..r*64+63 of the 128-row A tile
    #define STA(p, kt, r) load_lds16(Xbf + (size_t)(row0 + (r)*64 + srow) * DD + (kt)*64 + scol, \
                                     ABUF(p) + (r)*8192 + wv*1024)
    #define STB(p, kt, r) load_lds16(Wt + (size_t)(col0 + (r)*64 + srow) * DD + (kt)*64 + scol, \
                                     BBUF(p) + (r)*8192 + wv*1024)

    // prologue: tiles 0,1 -> bufs 0,1 (6 loads each per wave)
    STA(0,0,0); STA(0,0,1); STB(0,0,0); STB(0,0,1); STB(0,0,2); STB(0,0,3);
    STA(1,1,0); STA(1,1,1); STB(1,1,0); STB(1,1,1); STB(1,1,2); STB(1,1,3);
    asm volatile("s_waitcnt vmcnt(6)" ::: "memory");
    __builtin_amdgcn_s_barrier();
    __builtin_amdgcn_sched_barrier(0);

    f32x4 acc[4][4] = {};
    const int arow_b = wm * 64 + (l & 15);
    const int brow_b = wn * 64 + (l & 15);
    const int cb_b = (l >> 4) * 16;

    for (int kt = 0; kt < 16; ++kt) {
        const int p = kt % 3, pn = (kt + 2) % 3;
        const bool more = (kt + 2) < 16;
#pragma unroll
        for (int q = 0; q < 4; ++q) {
            if (more) {                     // stage tile kt+2 into buf pn (freed by tile kt-1)
                if (q == 0)      { STA(pn, kt + 2, 0); STA(pn, kt + 2, 1); }
                else if (q == 1) { STB(pn, kt + 2, 0); STB(pn, kt + 2, 1); }
                else if (q == 2) { STB(pn, kt + 2, 2); }
                else             { STB(pn, kt + 2, 3); }
            }
            const int mf0 = (q >> 1) * 2, nf0 = (q & 1) * 2;
            short8 a[2][2], bf8[2][2];
#pragma unroll
            for (int i = 0; i < 2; ++i) {
                const int ar = arow_b + (mf0 + i) * 16;
                const int br = brow_b + (nf0 + i) * 16;
#pragma unroll
                for (int ks = 0; ks < 2; ++ks) {
                    a[i][ks]   = *(const short8*)(ABUF(p) + ar * 128 + ((cb_b + ks * 64) ^ ((ar & 7) << 4)));
                    bf8[i][ks] = *(const short8*)(BBUF(p) + br * 128 + ((cb_b + ks * 64) ^ ((br & 7) << 4)));
                }
            }
            __builtin_amdgcn_s_setprio(1);
#pragma unroll
            for (int i = 0; i < 2; ++i)
#pragma unroll
                for (int j = 0; j < 2; ++j) {
                    acc[mf0 + i][nf0 + j] = __builtin_amdgcn_mfma_f32_16x16x32_bf16(a[i][0], bf8[j][0], acc[mf0 + i][nf0 + j], 0, 0, 0);
                    acc[mf0 + i][nf0 + j] = __builtin_amdgcn_mfma_f32_16x16x32_bf16(a[i][1], bf8[j][1], acc[mf0 + i][nf0 + j], 0, 0, 0);
                }
            __builtin_amdgcn_s_setprio(0);
            if (q == 3 && kt < 15) {
                if (more) asm volatile("s_waitcnt vmcnt(6)" ::: "memory");
                else      asm volatile("s_waitcnt vmcnt(0)" ::: "memory");
            }
            __builtin_amdgcn_s_barrier();
            __builtin_amdgcn_sched_barrier(0);
        }
    }

    // ---------- fused epilogue ----------
    const int region = by >> 2;
    const int h = ((by & 3) << 2) + wn;
    const int rg = row0 + wm * 64;
    const int b = rg >> 12;
    const int sb = rg & 4095;
    const size_t bh = (size_t)(b * HH + h);
    const int dd = l & 15;
    const int jbase = ((by & 3) << 8) + wn * 64;

    if (region == 0) {
        float bias[4];
#pragma unroll
        for (int nf = 0; nf < 4; ++nf) bias[nf] = bq[jbase + nf * 16 + dd];
#pragma unroll
        for (int mf = 0; mf < 4; ++mf) {
            float ds4[4];
#pragma unroll
            for (int g = 0; g < 4; ++g) {
                const int s = sb + mf * 16 + ((l >> 4) << 2) + g;
                float dsum = 0.f;
#pragma unroll
                for (int nf = 0; nf < 4; ++nf) {
                    u16 hv = f2bf((acc[mf][nf][g] + bias[nf]) * 0.125f);
                    Qh[(bh * SS + s) * HDD + nf * 16 + dd] = hv;
                    float fv = bf2f(hv);
                    dsum += fv * fv;
                }
                dsum += __shfl_xor(dsum, 1);
                dsum += __shfl_xor(dsum, 2);
                dsum += __shfl_xor(dsum, 4);
                dsum += __shfl_xor(dsum, 8);
                ds4[g] = 0.5f * dsum;
            }
            if (dd == 0)
                *(float4*)(dq + bh * SS + sb + mf * 16 + ((l >> 4) << 2)) =
                    make_float4(ds4[0], ds4[1], ds4[2], ds4[3]);
        }
    } else if (region == 1) {
        float bias[4];
#pragma unroll
        for (int nf = 0; nf < 4; ++nf) bias[nf] = bk[jbase + nf * 16 + dd];
#pragma unroll
        for (int mf = 0; mf < 4; ++mf) {
            float ds4[4];
#pragma unroll
            for (int g = 0; g < 4; ++g) {
                const int s = sb + mf * 16 + ((l >> 4) << 2) + g;
                const float m = mask[b * SS + s];
                float dsum = 0.f;
#pragma unroll
                for (int nf = 0; nf < 4; ++nf) {
                    u16 hv = f2bf((acc[mf][nf][g] + bias[nf]) * m * 0.125f);
                    Kh[(bh * SS + s) * HDD + nf * 16 + dd] = hv;
                    float fv = bf2f(hv);
                    dsum += fv * fv;
                }
                dsum += __shfl_xor(dsum, 1);
                dsum += __shfl_xor(dsum, 2);
                dsum += __shfl_xor(dsum, 4);
                dsum += __shfl_xor(dsum, 8);
                ds4[g] = 0.5f * dsum;
            }
            if (dd == 0)
                *(float4*)(dk + bh * SS + sb + mf * 16 + ((l >> 4) << 2)) =
                    make_float4(ds4[0], ds4[1], ds4[2], ds4[3]);
        }
    } else {
        float bias[4];
#pragma unroll
        for (int nf = 0; nf < 4; ++nf) bias[nf] = bv[jbase + nf * 16 + dd];
#pragma unroll
        for (int mf = 0; mf < 4; ++mf) {
            const int s0 = sb + mf * 16 + ((l >> 4) << 2);
#pragma unroll
            for (int nf = 0; nf < 4; ++nf) {
                ushort4_t pk;
#pragma unroll
                for (int g = 0; g < 4; ++g) {
                    const float m = mask[b * SS + s0 + g];
                    pk[g] = f2bf((acc[mf][nf][g] + bias[nf]) * m);
                }
                *(ushort4_t*)(Vt + (bh * HDD + nf * 16 + dd) * SS + s0) = pk;
            }
        }
    }
    #undef ABUF
    #undef BBUF
    #undef STA
    #undef STB
}

// ---------------- stab: global max of u_k per (b,h) ----------------
__global__ __launch_bounds__(256, 2) void stab_kernel(
    const u16* __restrict__ Kh, const u16* __restrict__ projb, u32* __restrict__ stabkey)
{
    __shared__ __align__(16) u16 Klds[64 * 64];
    __shared__ float red4[4];
    const int tid = threadIdx.x, l = tid & 63, wv = tid >> 6;
    const int rt = blockIdx.x, bh = blockIdx.y;
    short8 pb[4][2];
#pragma unroll
    for (int nf = 0; nf < 4; ++nf)
#pragma unroll
        for (int ks = 0; ks < 2; ++ks)
            pb[nf][ks] = *(const short8*)(projb + (wv * 64 + nf * 16 + (l & 15)) * HDD + ks * 32 + (l >> 4) * 8);
    const size_t sbase = (size_t)bh * SS + rt * 64;
#pragma unroll
    for (int c = 0; c < 2; ++c) {
        const int rb = wv * 16 + c * 8;
        const int r = rb + (l >> 3);
        load_lds16(Kh + (sbase + r) * HDD + (((l & 7) ^ (r & 7)) * 8), (char*)Klds + rb * 128);
    }
    __syncthreads();
    float mx = -3.0e38f;
#pragma unroll
    for (int sf = 0; sf < 4; ++sf) {
        const int s = sf * 16 + (l & 15);
        f32x4 u4[4] = {};
#pragma unroll
        for (int ks = 0; ks < 2; ++ks) {
            short8 ak = *(const short8*)((const char*)Klds + s * 128 + ((ks * 64 + (l >> 4) * 16) ^ ((s & 7) << 4)));
#pragma unroll
            for (int nf = 0; nf < 4; ++nf)
                u4[nf] = __builtin_amdgcn_mfma_f32_16x16x32_bf16(ak, pb[nf][ks], u4[nf], 0, 0, 0);
        }
#pragma unroll
        for (int nf = 0; nf < 4; ++nf)
#pragma unroll
            for (int g = 0; g < 4; ++g) mx = fmaxf(mx, u4[nf][g]);
    }
#pragma unroll
    for (int o = 1; o < 64; o <<= 1) mx = fmaxf(mx, __shfl_xor(mx, o));
    if (l == 0) red4[wv] = mx;
    __syncthreads();
    if (tid == 0) {
        float m2 = fmaxf(fmaxf(red4[0], red4[1]), fmaxf(red4[2], red4[3]));
        atomicMax(stabkey + bh, fenc(m2));
    }
}

// ---------------- kv_fused: k' on the fly, kv = k'^T Vs + ksum ----------------
__global__ __launch_bounds__(256, 2) void kv_fused(
    const u16* __restrict__ Kh, const u16* __restrict__ Vt,
    const u16* __restrict__ projb, const float* __restrict__ dk,
    const u32* __restrict__ stabkey,
    float* __restrict__ kv_part, float* __restrict__ ksum_part)
{
    __shared__ __align__(16) u16 Klds[64 * 64];
    __shared__ __align__(16) u16 Vlds[64 * 64];
    __shared__ __align__(16) u16 Kp[256 * 64];
    const int tid = threadIdx.x, l = tid & 63, wv = tid >> 6;
    const int ck = blockIdx.x, bh = blockIdx.y;
    const float stab = fdec(stabkey[bh]);
    short8 pb[4][2];
#pragma unroll
    for (int nf = 0; nf < 4; ++nf)
#pragma unroll
        for (int ks = 0; ks < 2; ++ks)
            pb[nf][ks] = *(const short8*)(projb + (wv * 64 + nf * 16 + (l & 15)) * HDD + ks * 32 + (l >> 4) * 8);
    f32x4 acc[4][4] = {};
    float ksc[4] = {0.f, 0.f, 0.f, 0.f};
    const size_t sbase = (size_t)bh * SS + ck * 512;
    for (int it = 0; it < 8; ++it) {
        const int s0 = it * 64;
#pragma unroll
        for (int c = 0; c < 2; ++c) {
            const int rb = wv * 16 + c * 8;
            const int r = rb + (l >> 3);
            const int sc = ((l & 7) ^ (r & 7)) * 8;
            load_lds16(Kh + (sbase + s0 + r) * HDD + sc, (char*)Klds + rb * 128);
            load_lds16(Vt + ((size_t)bh * HDD + r) * SS + ck * 512 + s0 + sc, (char*)Vlds + rb * 128);
        }
        __syncthreads();
#pragma unroll
        for (int sf = 0; sf < 4; ++sf) {
            const int s = sf * 16 + (l & 15);
            f32x4 u4[4] = {};
#pragma unroll
            for (int ks = 0; ks < 2; ++ks) {
                short8 ak = *(const short8*)((const char*)Klds + s * 128 + ((ks * 64 + (l >> 4) * 16) ^ ((s & 7) << 4)));
#pragma unroll
                for (int nf = 0; nf < 4; ++nf)
                    u4[nf] = __builtin_amdgcn_mfma_f32_16x16x32_bf16(ak, pb[nf][ks], u4[nf], 0, 0, 0);
            }
            const int srow = sf * 16 + (l >> 4) * 4;
            const float4 dkv = *(const float4*)(dk + sbase + s0 + srow);
#pragma unroll
            for (int nf = 0; nf < 4; ++nf) {
                const int m = wv * 64 + nf * 16 + (l & 15);
                u16 h0 = f2bf(0.0625f * (__expf(u4[nf][0] - dkv.x - stab) + 1e-4f));
                u16 h1 = f2bf(0.0625f * (__expf(u4[nf][1] - dkv.y - stab) + 1e-4f));
                u16 h2 = f2bf(0.0625f * (__expf(u4[nf][2] - dkv.z - stab) + 1e-4f));
                u16 h3 = f2bf(0.0625f * (__expf(u4[nf][3] - dkv.w - stab) + 1e-4f));
                ksc[nf] += bf2f(h0) + bf2f(h1) + bf2f(h2) + bf2f(h3);
                uint2 w; w.x = (u32)h0 | ((u32)h1 << 16); w.y = (u32)h2 | ((u32)h3 << 16);
                *(uint2*)((char*)Kp + m * 128 + ((srow * 2) ^ ((m & 7) << 4))) = w;
            }
        }
#pragma unroll
        for (int ks = 0; ks < 2; ++ks) {
            short8 am[4], bv8[4];
#pragma unroll
            for (int mf = 0; mf < 4; ++mf) {
                const int m = wv * 64 + mf * 16 + (l & 15);
                am[mf] = *(const short8*)((const char*)Kp + m * 128 + ((ks * 64 + (l >> 4) * 16) ^ ((m & 7) << 4)));
            }
#pragma unroll
            for (int nf = 0; nf < 4; ++nf) {
                const int d = nf * 16 + (l & 15);
                bv8[nf] = *(const short8*)((const char*)Vlds + d * 128 + ((ks * 64 + (l >> 4) * 16) ^ ((d & 7) << 4)));
            }
#pragma unroll
            for (int mf = 0; mf < 4; ++mf)
#pragma unroll
                for (int nf = 0; nf < 4; ++nf)
                    acc[mf][nf] = __builtin_amdgcn_mfma_f32_16x16x32_bf16(am[mf], bv8[nf], acc[mf][nf], 0, 0, 0);
        }
        __syncthreads();
    }
    const size_t pbase = (size_t)ck * BHN + bh;
#pragma unroll
    for (int nf = 0; nf < 4; ++nf) {
        float v = ksc[nf];
        v += __shfl_xor(v, 16);
        v += __shfl_xor(v, 32);
        if (l < 16) ksum_part[pbase * MM + wv * 64 + nf * 16 + l] = v;
    }
#pragma unroll
    for (int mf = 0; mf < 4; ++mf)
#pragma unroll
        for (int nf = 0; nf < 4; ++nf)
            *(f32x4*)(kv_part + (pbase * HDD + nf * 16 + (l & 15)) * MM + wv * 64 + mf * 16 + (l >> 4) * 4) = acc[mf][nf];
}

// ---------------- reduce partials -> Bmat[bh][80][256] bf16 ----------------
__global__ void reduceB2(const float* __restrict__ kv_part, const float* __restrict__ ksum_part,
                         u16* __restrict__ Bmat) {
    const int bh = blockIdx.x, n = blockIdx.y, t = threadIdx.x;
    float s = 0.f;
    if (n < 64) {
#pragma unroll
        for (int ck = 0; ck < 8; ++ck) s += kv_part[(((size_t)ck * BHN + bh) * HDD + n) * MM + t];
    } else if (n == 64) {
#pragma unroll
        for (int ck = 0; ck < 8; ++ck) s += ksum_part[((size_t)ck * BHN + bh) * MM + t];
    }
    Bmat[((size_t)bh * 80 + n) * MM + t] = (n <= 64) ? f2bf(s) : (u16)0;
}

// ---------------- out_fused: q' on the fly, out = (q' @ [kv|ksum]) * z ----------------
__global__ __launch_bounds__(256, 2) void out_fused(
    const u16* __restrict__ Qh, const u16* __restrict__ projb,
    const float* __restrict__ dq, const u16* __restrict__ Bmat,
    float* __restrict__ out)
{
    __shared__ __align__(16) u16 Blds[80 * 256];
    __shared__ __align__(16) u16 Qlds[32 * 64];
    __shared__ __align__(16) u16 qlds[32 * 256];
    __shared__ float red[4][32];
    const int tid = threadIdx.x, l = tid & 63, wv = tid >> 6;
    const int rt = blockIdx.x, bh = blockIdx.y;
#pragma unroll
    for (int c = 0; c < 10; ++c) {
        const int r = (wv * 10 + c) * 2 + (l >> 5);
        load_lds16(Bmat + (size_t)bh * 20480 + r * 256 + (((l & 31) ^ (r & 7)) * 8),
                   (char*)Blds + (wv * 10 + c) * 1024);
    }
    const size_t srowbase = (size_t)bh * SS + rt * 32;
    {
        const int rb = wv * 8;
        const int r = rb + (l >> 3);
        load_lds16(Qh + (srowbase + r) * HDD + (((l & 7) ^ (r & 7)) * 8), (char*)Qlds + rb * 128);
    }
    short8 pa[4][2];
#pragma unroll
    for (int mf = 0; mf < 4; ++mf)
#pragma unroll
        for (int ks = 0; ks < 2; ++ks)
            pa[mf][ks] = *(const short8*)(projb + (wv * 64 + mf * 16 + (l & 15)) * HDD + ks * 32 + (l >> 4) * 8);
    __syncthreads();
    f32x4 u[4][2] = {};
#pragma unroll
    for (int ks = 0; ks < 2; ++ks) {
        short8 bq8[2];
#pragma unroll
        for (int nf = 0; nf < 2; ++nf) {
            const int s = nf * 16 + (l & 15);
            bq8[nf] = *(const short8*)((const char*)Qlds + s * 128 + ((ks * 64 + (l >> 4) * 16) ^ ((s & 7) << 4)));
        }
#pragma unroll
        for (int mf = 0; mf < 4; ++mf)
#pragma unroll
            for (int nf = 0; nf < 2; ++nf)
                u[mf][nf] = __builtin_amdgcn_mfma_f32_16x16x32_bf16(pa[mf][ks], bq8[nf], u[mf][nf], 0, 0, 0);
    }
#pragma unroll
    for (int nf = 0; nf < 2; ++nf) {
        float v = -3.0e38f;
#pragma unroll
        for (int mf = 0; mf < 4; ++mf)
#pragma unroll
            for (int g = 0; g < 4; ++g) v = fmaxf(v, u[mf][nf][g]);
        v = fmaxf(v, __shfl_xor(v, 16));
        v = fmaxf(v, __shfl_xor(v, 32));
        if ((l >> 4) == 0) red[wv][nf * 16 + l] = v;
    }
    __syncthreads();
#pragma unroll
    for (int nf = 0; nf < 2; ++nf) {
        const int s = nf * 16 + (l & 15);
        const float mx = fmaxf(fmaxf(red[0][s], red[1][s]), fmaxf(red[2][s], red[3][s]));
        const float dg = dq[srowbase + s];
#pragma unroll
        for (int mf = 0; mf < 4; ++mf) {
            u16 h0 = f2bf(0.0625f * (__expf(u[mf][nf][0] - dg - mx) + 1e-4f));
            u16 h1 = f2bf(0.0625f * (__expf(u[mf][nf][1] - dg - mx) + 1e-4f));
            u16 h2 = f2bf(0.0625f * (__expf(u[mf][nf][2] - dg - mx) + 1e-4f));
            u16 h3 = f2bf(0.0625f * (__expf(u[mf][nf][3] - dg - mx) + 1e-4f));
            uint2 w; w.x = (u32)h0 | ((u32)h1 << 16); w.y = (u32)h2 | ((u32)h3 << 16);
            const int mb = (wv * 64 + mf * 16 + (l >> 4) * 4) * 2;
            *(uint2*)((char*)qlds + s * 512 + (mb ^ ((s & 7) << 4))) = w;
        }
    }
    __syncthreads();
    f32x4 acc[2][2] = {};
    for (int kt = 0; kt < 8; ++kt) {
        short8 aq[2], bb[2];
#pragma unroll
        for (int mf = 0; mf < 2; ++mf) {
            const int s = mf * 16 + (l & 15);
            aq[mf] = *(const short8*)((const char*)qlds + s * 512 + ((kt * 64 + (l >> 4) * 16) ^ ((s & 7) << 4)));
        }
        {
            const int n0 = wv * 16 + (l & 15);
            bb[0] = *(const short8*)((const char*)Blds + n0 * 512 + ((kt * 64 + (l >> 4) * 16) ^ ((n0 & 7) << 4)));
            const int n1 = 64 + (l & 15);
            bb[1] = *(const short8*)((const char*)Blds + n1 * 512 + ((kt * 64 + (l >> 4) * 16) ^ ((n1 & 7) << 4)));
        }
#pragma unroll
        for (int mf = 0; mf < 2; ++mf)
#pragma unroll
            for (int nf = 0; nf < 2; ++nf)
                acc[mf][nf] = __builtin_amdgcn_mfma_f32_16x16x32_bf16(aq[mf], bb[nf], acc[mf][nf], 0, 0, 0);
    }
    const int b = bh >> 4, h = bh & 15;
#pragma unroll
    for (int mf = 0; mf < 2; ++mf) {
#pragma unroll
        for (int g = 0; g < 4; ++g) {
            const float den = __shfl(acc[mf][1][g], (l & 48));
            const float z = 1.0f / (den + 1e-6f);
            const int s = rt * 32 + mf * 16 + (l >> 4) * 4 + g;
            out[((size_t)b * SS + s) * DD + h * HDD + wv * 16 + (l & 15)] = acc[mf][0][g] * z;
        }
    }
}

// ---------------- launcher ----------------
extern "C" void kernel_launch(void* const* d_in, const int* in_sizes, int n_in,
                              void* d_out, int out_size, void* d_ws, size_t ws_size,
                              hipStream_t stream)
{
    const float* X    = (const float*)d_in[0];
    const float* mask = (const float*)d_in[1];
    const float* Wq   = (const float*)d_in[2];
    const float* bq   = (const float*)d_in[3];
    const float* Wk   = (const float*)d_in[4];
    const float* bk   = (const float*)d_in[5];
    const float* Wv   = (const float*)d_in[6];
    const float* bv   = (const float*)d_in[7];
    const float* proj = (const float*)d_in[8];
    float* out = (float*)d_out;

    char* p = (char*)d_ws;
    u16* Xbf = (u16*)p;                            // 32 MB (aliased by kv_part after gemm1)
    float* kv_part = (float*)p; p += 33554432;
    u16* Wt = (u16*)p;    p += 6291456;
    u16* projb = (u16*)p; p += 32768;
    u16* Qh = (u16*)p;    p += 33554432;
    u16* Kh = (u16*)p;    p += 33554432;
    u16* Vt = (u16*)p;    p += 33554432;
    float* dq = (float*)p; p += 1048576;
    float* dk = (float*)p; p += 1048576;
    u32* stabkey = (u32*)p; p += 256;
    float* ksum_part = (float*)p; p += 524288;
    u16* Bmat = (u16*)p;  p += 2621440;
    if (ws_size < 145785088ull) return;

    hipFuncSetAttribute((const void*)gemm1_8ph, hipFuncAttributeMaxDynamicSharedMemorySize, 147456);

    hipMemsetAsync(stabkey, 0, 256, stream);
    conv_bf16<<<16384, 256, 0, stream>>>(X, Xbf, 4194304);
    conv_w<<<dim3(48, 16), 256, 0, stream>>>(Wq, Wk, Wv, Wt);
    conv_bf16<<<16, 256, 0, stream>>>(proj, projb, 4096);
    gemm1_8ph<<<1536, 512, 147456, stream>>>(Xbf, Wt, bq, bk, bv, mask, Qh, Kh, Vt, dq, dk);
    stab_kernel<<<dim3(64, 64), 256, 0, stream>>>(Kh, projb, stabkey);
    kv_fused<<<dim3(8, 64), 256, 0, stream>>>(Kh, Vt, projb, dk, stabkey, kv_part, ksum_part);
    reduceB2<<<dim3(64, 80), 256, 0, stream>>>(kv_part, ksum_part, Bmat);
    out_fused<<<dim3(128, 64), 256, 0, stream>>>(Qh, projb, dq, Bmat, out);
}

// Round 4
// 298.433 us; speedup vs baseline: 1.1346x; 1.0824x over previous
//
#include <hip/hip_runtime.h>
#include <stdint.h>

#define DEVI static __device__ __forceinline__

typedef unsigned short u16;
typedef unsigned int u32;
typedef __attribute__((ext_vector_type(8))) short short8;
typedef __attribute__((ext_vector_type(4))) float f32x4;
typedef __attribute__((ext_vector_type(4))) unsigned short ushort4_t;

#define BB 4
#define SS 4096
#define DD 1024
#define HH 16
#define HDD 64
#define MM 256
#define BHN 64

DEVI u16 f2bf(float f) {
    u32 u = __float_as_uint(f);
    u += 0x7fffu + ((u >> 16) & 1u);
    return (u16)(u >> 16);
}
DEVI float bf2f(u16 h) { return __uint_as_float(((u32)h) << 16); }
DEVI u32 fenc(float f) {
    u32 u = __float_as_uint(f);
    return (u & 0x80000000u) ? ~u : (u | 0x80000000u);
}
DEVI float fdec(u32 k) {
    u32 u = (k & 0x80000000u) ? (k & 0x7fffffffu) : ~k;
    return __uint_as_float(u);
}

typedef __attribute__((address_space(1))) const unsigned int as1_u32;
typedef __attribute__((address_space(3))) unsigned int as3_u32;
DEVI void load_lds16(const void* g, void* lds) {
    __builtin_amdgcn_global_load_lds((as1_u32*)g, (as3_u32*)lds, 16, 0, 0);
}

// ---------------- conversion kernels ----------------

__global__ void conv_bf16(const float* __restrict__ src, u16* __restrict__ dst, int n4) {
    int i = blockIdx.x * 256 + threadIdx.x;
    if (i < n4) {
        float4 v = reinterpret_cast<const float4*>(src)[i];
        ushort4_t o = { f2bf(v.x), f2bf(v.y), f2bf(v.z), f2bf(v.w) };
        reinterpret_cast<ushort4_t*>(dst)[i] = o;
    }
}

__global__ void conv_w(const float* __restrict__ Wq, const float* __restrict__ Wk,
                       const float* __restrict__ Wv, u16* __restrict__ Wt) {
    __shared__ float tile[64][65];
    const int jt = blockIdx.x, kt = blockIdx.y;
    const float* src = (jt < 16) ? Wq : (jt < 32) ? Wk : Wv;
    const int j0 = (jt & 15) * 64, k0 = kt * 64;
    const int t = threadIdx.x;
    for (int i = 0; i < 16; ++i) {
        int lin = t + i * 256;
        int kl = lin >> 6, jl = lin & 63;
        tile[kl][jl] = src[(size_t)(k0 + kl) * DD + j0 + jl];
    }
    __syncthreads();
    const int jg0 = jt * 64;
    for (int i = 0; i < 16; ++i) {
        int lin = t + i * 256;
        int jl = lin >> 6, kl = lin & 63;
        Wt[(size_t)(jg0 + jl) * DD + k0 + kl] = f2bf(tile[kl][jl]);
    }
}

// ---------------- QKV projection GEMM: BM=256,BN=256,BK=64; per-wave 128x64 ----------------
// 512 thr = 8 waves (2M x 4N). LDS 2 x (32KB A + 32KB B) = 128KB, double-buffered.
// Prefetch depth 1: issue next tile's 8 global_load_lds across the 4 sub-phases,
// drain vmcnt(0) only at the tile boundary. Fused epilogue: Q/K/V scatter + diag.
__global__ __launch_bounds__(512, 2) void gemm1_big(
    const u16* __restrict__ Xbf, const u16* __restrict__ Wt,
    const float* __restrict__ bq, const float* __restrict__ bk, const float* __restrict__ bv,
    const float* __restrict__ mask,
    u16* __restrict__ Qh, u16* __restrict__ Kh, u16* __restrict__ Vt,
    float* __restrict__ dq, float* __restrict__ dk)
{
    extern __shared__ __align__(16) char smem[];
    const int tid = threadIdx.x, l = tid & 63, wv = tid >> 6;
    const int wm = wv >> 2, wn = wv & 3;
    // XCD-chunked mapping: each XCD owns 8 row-panels; col-tiles fastest.
    const int bid = blockIdx.x;
    const int xcd = bid & 7, i6 = bid >> 3;          // 768 blocks = 8 * 96
    const int bx = xcd * 8 + i6 / 12, by = i6 % 12;
    const int row0 = bx * 256, col0 = by * 256;

    const int srow = tid >> 3;                       // 0..63 per staging round
    const int scol = ((tid & 7) ^ (srow & 7)) * 8;   // pre-swizzled source col (elems)

    #define ABUF(p) ((char*)smem + (p) * 32768)
    #define BBUF(p) ((char*)smem + 65536 + (p) * 32768)
    #define STA(p, kt, r) load_lds16(Xbf + (size_t)(row0 + (r)*64 + srow) * DD + (kt)*64 + scol, \
                                     ABUF(p) + (r)*8192 + wv*1024)
    #define STB(p, kt, r) load_lds16(Wt + (size_t)(col0 + (r)*64 + srow) * DD + (kt)*64 + scol, \
                                     BBUF(p) + (r)*8192 + wv*1024)

    // prologue: tile 0 -> buf 0
    STA(0,0,0); STA(0,0,1); STA(0,0,2); STA(0,0,3);
    STB(0,0,0); STB(0,0,1); STB(0,0,2); STB(0,0,3);
    asm volatile("s_waitcnt vmcnt(0)" ::: "memory");
    __builtin_amdgcn_s_barrier();
    __builtin_amdgcn_sched_barrier(0);

    f32x4 acc[8][4] = {};
    const int arow_b = wm * 128 + (l & 15);
    const int brow_b = wn * 64 + (l & 15);
    const int cb_b = (l >> 4) * 16;
    const int lx = (l & 7) << 4;                     // swizzle XOR (row&7)<<4 == (l&7)<<4 for frag rows

    for (int kt = 0; kt < 16; ++kt) {
        const int p = kt & 1, pn = p ^ 1;
        const bool more = (kt + 1) < 16;
        short8 bfr[4][2];
#pragma unroll
        for (int q = 0; q < 4; ++q) {
            if (more) {                              // stage tile kt+1 into the buffer freed at last barrier
                if (q == 0)      { STA(pn, kt + 1, 0); STA(pn, kt + 1, 1); }
                else if (q == 1) { STA(pn, kt + 1, 2); STA(pn, kt + 1, 3); }
                else if (q == 2) { STB(pn, kt + 1, 0); STB(pn, kt + 1, 1); }
                else             { STB(pn, kt + 1, 2); STB(pn, kt + 1, 3); }
            }
            if (q == 0) {
#pragma unroll
                for (int nf = 0; nf < 4; ++nf) {
                    const int br = brow_b + nf * 16;
#pragma unroll
                    for (int ks = 0; ks < 2; ++ks)
                        bfr[nf][ks] = *(const short8*)(BBUF(p) + br * 128 + ((cb_b + ks * 64) ^ lx));
                }
            }
            short8 a[2][2];
#pragma unroll
            for (int i = 0; i < 2; ++i) {
                const int ar = arow_b + (q * 2 + i) * 16;
#pragma unroll
                for (int ks = 0; ks < 2; ++ks)
                    a[i][ks] = *(const short8*)(ABUF(p) + ar * 128 + ((cb_b + ks * 64) ^ lx));
            }
            __builtin_amdgcn_s_setprio(1);
#pragma unroll
            for (int i = 0; i < 2; ++i)
#pragma unroll
                for (int nf = 0; nf < 4; ++nf) {
                    acc[q*2+i][nf] = __builtin_amdgcn_mfma_f32_16x16x32_bf16(a[i][0], bfr[nf][0], acc[q*2+i][nf], 0, 0, 0);
                    acc[q*2+i][nf] = __builtin_amdgcn_mfma_f32_16x16x32_bf16(a[i][1], bfr[nf][1], acc[q*2+i][nf], 0, 0, 0);
                }
            __builtin_amdgcn_s_setprio(0);
            __builtin_amdgcn_sched_barrier(0);
        }
        asm volatile("s_waitcnt vmcnt(0)" ::: "memory");
        __builtin_amdgcn_s_barrier();
        __builtin_amdgcn_sched_barrier(0);
    }

    // ---------- fused epilogue ----------
    const int region = by >> 2;
    const int h = ((by & 3) << 2) + wn;
    const int rg = row0 + wm * 128;
    const int b = rg >> 12;
    const int sb = rg & 4095;
    const size_t bh = (size_t)(b * HH + h);
    const int dd = l & 15;
    const int jbase = ((by & 3) << 8) + wn * 64;

    if (region == 0) {
        float bias[4];
#pragma unroll
        for (int nf = 0; nf < 4; ++nf) bias[nf] = bq[jbase + nf * 16 + dd];
#pragma unroll
        for (int mf = 0; mf < 8; ++mf) {
            float ds4[4];
#pragma unroll
            for (int g = 0; g < 4; ++g) {
                const int s = sb + mf * 16 + ((l >> 4) << 2) + g;
                float dsum = 0.f;
#pragma unroll
                for (int nf = 0; nf < 4; ++nf) {
                    u16 hv = f2bf((acc[mf][nf][g] + bias[nf]) * 0.125f);
                    Qh[(bh * SS + s) * HDD + nf * 16 + dd] = hv;
                    float fv = bf2f(hv);
                    dsum += fv * fv;
                }
                dsum += __shfl_xor(dsum, 1);
                dsum += __shfl_xor(dsum, 2);
                dsum += __shfl_xor(dsum, 4);
                dsum += __shfl_xor(dsum, 8);
                ds4[g] = 0.5f * dsum;
            }
            if (dd == 0)
                *(float4*)(dq + bh * SS + sb + mf * 16 + ((l >> 4) << 2)) =
                    make_float4(ds4[0], ds4[1], ds4[2], ds4[3]);
        }
    } else if (region == 1) {
        float bias[4];
#pragma unroll
        for (int nf = 0; nf < 4; ++nf) bias[nf] = bk[jbase + nf * 16 + dd];
#pragma unroll
        for (int mf = 0; mf < 8; ++mf) {
            float ds4[4];
#pragma unroll
            for (int g = 0; g < 4; ++g) {
                const int s = sb + mf * 16 + ((l >> 4) << 2) + g;
                const float m = mask[b * SS + s];
                float dsum = 0.f;
#pragma unroll
                for (int nf = 0; nf < 4; ++nf) {
                    u16 hv = f2bf((acc[mf][nf][g] + bias[nf]) * m * 0.125f);
                    Kh[(bh * SS + s) * HDD + nf * 16 + dd] = hv;
                    float fv = bf2f(hv);
                    dsum += fv * fv;
                }
                dsum += __shfl_xor(dsum, 1);
                dsum += __shfl_xor(dsum, 2);
                dsum += __shfl_xor(dsum, 4);
                dsum += __shfl_xor(dsum, 8);
                ds4[g] = 0.5f * dsum;
            }
            if (dd == 0)
                *(float4*)(dk + bh * SS + sb + mf * 16 + ((l >> 4) << 2)) =
                    make_float4(ds4[0], ds4[1], ds4[2], ds4[3]);
        }
    } else {
        float bias[4];
#pragma unroll
        for (int nf = 0; nf < 4; ++nf) bias[nf] = bv[jbase + nf * 16 + dd];
#pragma unroll
        for (int mf = 0; mf < 8; ++mf) {
            const int s0 = sb + mf * 16 + ((l >> 4) << 2);
#pragma unroll
            for (int nf = 0; nf < 4; ++nf) {
                ushort4_t pk;
#pragma unroll
                for (int g = 0; g < 4; ++g) {
                    const float m = mask[b * SS + s0 + g];
                    pk[g] = f2bf((acc[mf][nf][g] + bias[nf]) * m);
                }
                *(ushort4_t*)(Vt + (bh * HDD + nf * 16 + dd) * SS + s0) = pk;
            }
        }
    }
    #undef ABUF
    #undef BBUF
    #undef STA
    #undef STB
}

// ---------------- stab: global max of u_k per (b,h) ----------------
__global__ __launch_bounds__(256, 2) void stab_kernel(
    const u16* __restrict__ Kh, const u16* __restrict__ projb, u32* __restrict__ stabkey)
{
    __shared__ __align__(16) u16 Klds[64 * 64];
    __shared__ float red4[4];
    const int tid = threadIdx.x, l = tid & 63, wv = tid >> 6;
    const int rt = blockIdx.x, bh = blockIdx.y;
    short8 pb[4][2];
#pragma unroll
    for (int nf = 0; nf < 4; ++nf)
#pragma unroll
        for (int ks = 0; ks < 2; ++ks)
            pb[nf][ks] = *(const short8*)(projb + (wv * 64 + nf * 16 + (l & 15)) * HDD + ks * 32 + (l >> 4) * 8);
    const size_t sbase = (size_t)bh * SS + rt * 64;
#pragma unroll
    for (int c = 0; c < 2; ++c) {
        const int rb = wv * 16 + c * 8;
        const int r = rb + (l >> 3);
        load_lds16(Kh + (sbase + r) * HDD + (((l & 7) ^ (r & 7)) * 8), (char*)Klds + rb * 128);
    }
    __syncthreads();
    float mx = -3.0e38f;
#pragma unroll
    for (int sf = 0; sf < 4; ++sf) {
        const int s = sf * 16 + (l & 15);
        f32x4 u4[4] = {};
#pragma unroll
        for (int ks = 0; ks < 2; ++ks) {
            short8 ak = *(const short8*)((const char*)Klds + s * 128 + ((ks * 64 + (l >> 4) * 16) ^ ((s & 7) << 4)));
#pragma unroll
            for (int nf = 0; nf < 4; ++nf)
                u4[nf] = __builtin_amdgcn_mfma_f32_16x16x32_bf16(ak, pb[nf][ks], u4[nf], 0, 0, 0);
        }
#pragma unroll
        for (int nf = 0; nf < 4; ++nf)
#pragma unroll
            for (int g = 0; g < 4; ++g) mx = fmaxf(mx, u4[nf][g]);
    }
#pragma unroll
    for (int o = 1; o < 64; o <<= 1) mx = fmaxf(mx, __shfl_xor(mx, o));
    if (l == 0) red4[wv] = mx;
    __syncthreads();
    if (tid == 0) {
        float m2 = fmaxf(fmaxf(red4[0], red4[1]), fmaxf(red4[2], red4[3]));
        atomicMax(stabkey + bh, fenc(m2));
    }
}

// ---------------- kv_fused: k' on the fly, kv = k'^T Vs + ksum ----------------
__global__ __launch_bounds__(256, 2) void kv_fused(
    const u16* __restrict__ Kh, const u16* __restrict__ Vt,
    const u16* __restrict__ projb, const float* __restrict__ dk,
    const u32* __restrict__ stabkey,
    float* __restrict__ kv_part, float* __restrict__ ksum_part)
{
    __shared__ __align__(16) u16 Klds[64 * 64];
    __shared__ __align__(16) u16 Vlds[64 * 64];
    __shared__ __align__(16) u16 Kp[256 * 64];
    const int tid = threadIdx.x, l = tid & 63, wv = tid >> 6;
    const int ck = blockIdx.x, bh = blockIdx.y;
    const float stab = fdec(stabkey[bh]);
    short8 pb[4][2];
#pragma unroll
    for (int nf = 0; nf < 4; ++nf)
#pragma unroll
        for (int ks = 0; ks < 2; ++ks)
            pb[nf][ks] = *(const short8*)(projb + (wv * 64 + nf * 16 + (l & 15)) * HDD + ks * 32 + (l >> 4) * 8);
    f32x4 acc[4][4] = {};
    float ksc[4] = {0.f, 0.f, 0.f, 0.f};
    const size_t sbase = (size_t)bh * SS + ck * 512;
    for (int it = 0; it < 8; ++it) {
        const int s0 = it * 64;
#pragma unroll
        for (int c = 0; c < 2; ++c) {
            const int rb = wv * 16 + c * 8;
            const int r = rb + (l >> 3);
            const int sc = ((l & 7) ^ (r & 7)) * 8;
            load_lds16(Kh + (sbase + s0 + r) * HDD + sc, (char*)Klds + rb * 128);
            load_lds16(Vt + ((size_t)bh * HDD + r) * SS + ck * 512 + s0 + sc, (char*)Vlds + rb * 128);
        }
        __syncthreads();
#pragma unroll
        for (int sf = 0; sf < 4; ++sf) {
            const int s = sf * 16 + (l & 15);
            f32x4 u4[4] = {};
#pragma unroll
            for (int ks = 0; ks < 2; ++ks) {
                short8 ak = *(const short8*)((const char*)Klds + s * 128 + ((ks * 64 + (l >> 4) * 16) ^ ((s & 7) << 4)));
#pragma unroll
                for (int nf = 0; nf < 4; ++nf)
                    u4[nf] = __builtin_amdgcn_mfma_f32_16x16x32_bf16(ak, pb[nf][ks], u4[nf], 0, 0, 0);
            }
            const int srow = sf * 16 + (l >> 4) * 4;
            const float4 dkv = *(const float4*)(dk + sbase + s0 + srow);
#pragma unroll
            for (int nf = 0; nf < 4; ++nf) {
                const int m = wv * 64 + nf * 16 + (l & 15);
                u16 h0 = f2bf(0.0625f * (__expf(u4[nf][0] - dkv.x - stab) + 1e-4f));
                u16 h1 = f2bf(0.0625f * (__expf(u4[nf][1] - dkv.y - stab) + 1e-4f));
                u16 h2 = f2bf(0.0625f * (__expf(u4[nf][2] - dkv.z - stab) + 1e-4f));
                u16 h3 = f2bf(0.0625f * (__expf(u4[nf][3] - dkv.w - stab) + 1e-4f));
                ksc[nf] += bf2f(h0) + bf2f(h1) + bf2f(h2) + bf2f(h3);
                uint2 w; w.x = (u32)h0 | ((u32)h1 << 16); w.y = (u32)h2 | ((u32)h3 << 16);
                *(uint2*)((char*)Kp + m * 128 + ((srow * 2) ^ ((m & 7) << 4))) = w;
            }
        }
#pragma unroll
        for (int ks = 0; ks < 2; ++ks) {
            short8 am[4], bv8[4];
#pragma unroll
            for (int mf = 0; mf < 4; ++mf) {
                const int m = wv * 64 + mf * 16 + (l & 15);
                am[mf] = *(const short8*)((const char*)Kp + m * 128 + ((ks * 64 + (l >> 4) * 16) ^ ((m & 7) << 4)));
            }
#pragma unroll
            for (int nf = 0; nf < 4; ++nf) {
                const int d = nf * 16 + (l & 15);
                bv8[nf] = *(const short8*)((const char*)Vlds + d * 128 + ((ks * 64 + (l >> 4) * 16) ^ ((d & 7) << 4)));
            }
#pragma unroll
            for (int mf = 0; mf < 4; ++mf)
#pragma unroll
                for (int nf = 0; nf < 4; ++nf)
                    acc[mf][nf] = __builtin_amdgcn_mfma_f32_16x16x32_bf16(am[mf], bv8[nf], acc[mf][nf], 0, 0, 0);
        }
        __syncthreads();
    }
    const size_t pbase = (size_t)ck * BHN + bh;
#pragma unroll
    for (int nf = 0; nf < 4; ++nf) {
        float v = ksc[nf];
        v += __shfl_xor(v, 16);
        v += __shfl_xor(v, 32);
        if (l < 16) ksum_part[pbase * MM + wv * 64 + nf * 16 + l] = v;
    }
#pragma unroll
    for (int mf = 0; mf < 4; ++mf)
#pragma unroll
        for (int nf = 0; nf < 4; ++nf)
            *(f32x4*)(kv_part + (pbase * HDD + nf * 16 + (l & 15)) * MM + wv * 64 + mf * 16 + (l >> 4) * 4) = acc[mf][nf];
}

// ---------------- reduce partials -> Bmat[bh][80][256] bf16 ----------------
__global__ void reduceB2(const float* __restrict__ kv_part, const float* __restrict__ ksum_part,
                         u16* __restrict__ Bmat) {
    const int bh = blockIdx.x, n = blockIdx.y, t = threadIdx.x;
    float s = 0.f;
    if (n < 64) {
#pragma unroll
        for (int ck = 0; ck < 8; ++ck) s += kv_part[(((size_t)ck * BHN + bh) * HDD + n) * MM + t];
    } else if (n == 64) {
#pragma unroll
        for (int ck = 0; ck < 8; ++ck) s += ksum_part[((size_t)ck * BHN + bh) * MM + t];
    }
    Bmat[((size_t)bh * 80 + n) * MM + t] = (n <= 64) ? f2bf(s) : (u16)0;
}

// ---------------- out_fused: q' on the fly, out = (q' @ [kv|ksum]) * z ----------------
__global__ __launch_bounds__(256, 2) void out_fused(
    const u16* __restrict__ Qh, const u16* __restrict__ projb,
    const float* __restrict__ dq, const u16* __restrict__ Bmat,
    float* __restrict__ out)
{
    __shared__ __align__(16) u16 Blds[80 * 256];
    __shared__ __align__(16) u16 Qlds[32 * 64];
    __shared__ __align__(16) u16 qlds[32 * 256];
    __shared__ float red[4][32];
    const int tid = threadIdx.x, l = tid & 63, wv = tid >> 6;
    const int rt = blockIdx.x, bh = blockIdx.y;
#pragma unroll
    for (int c = 0; c < 10; ++c) {
        const int r = (wv * 10 + c) * 2 + (l >> 5);
        load_lds16(Bmat + (size_t)bh * 20480 + r * 256 + (((l & 31) ^ (r & 7)) * 8),
                   (char*)Blds + (wv * 10 + c) * 1024);
    }
    const size_t srowbase = (size_t)bh * SS + rt * 32;
    {
        const int rb = wv * 8;
        const int r = rb + (l >> 3);
        load_lds16(Qh + (srowbase + r) * HDD + (((l & 7) ^ (r & 7)) * 8), (char*)Qlds + rb * 128);
    }
    short8 pa[4][2];
#pragma unroll
    for (int mf = 0; mf < 4; ++mf)
#pragma unroll
        for (int ks = 0; ks < 2; ++ks)
            pa[mf][ks] = *(const short8*)(projb + (wv * 64 + mf * 16 + (l & 15)) * HDD + ks * 32 + (l >> 4) * 8);
    __syncthreads();
    f32x4 u[4][2] = {};
#pragma unroll
    for (int ks = 0; ks < 2; ++ks) {
        short8 bq8[2];
#pragma unroll
        for (int nf = 0; nf < 2; ++nf) {
            const int s = nf * 16 + (l & 15);
            bq8[nf] = *(const short8*)((const char*)Qlds + s * 128 + ((ks * 64 + (l >> 4) * 16) ^ ((s & 7) << 4)));
        }
#pragma unroll
        for (int mf = 0; mf < 4; ++mf)
#pragma unroll
            for (int nf = 0; nf < 2; ++nf)
                u[mf][nf] = __builtin_amdgcn_mfma_f32_16x16x32_bf16(pa[mf][ks], bq8[nf], u[mf][nf], 0, 0, 0);
    }
#pragma unroll
    for (int nf = 0; nf < 2; ++nf) {
        float v = -3.0e38f;
#pragma unroll
        for (int mf = 0; mf < 4; ++mf)
#pragma unroll
            for (int g = 0; g < 4; ++g) v = fmaxf(v, u[mf][nf][g]);
        v = fmaxf(v, __shfl_xor(v, 16));
        v = fmaxf(v, __shfl_xor(v, 32));
        if ((l >> 4) == 0) red[wv][nf * 16 + l] = v;
    }
    __syncthreads();
#pragma unroll
    for (int nf = 0; nf < 2; ++nf) {
        const int s = nf * 16 + (l & 15);
        const float mx = fmaxf(fmaxf(red[0][s], red[1][s]), fmaxf(red[2][s], red[3][s]));
        const float dg = dq[srowbase + s];
#pragma unroll
        for (int mf = 0; mf < 4; ++mf) {
            u16 h0 = f2bf(0.0625f * (__expf(u[mf][nf][0] - dg - mx) + 1e-4f));
            u16 h1 = f2bf(0.0625f * (__expf(u[mf][nf][1] - dg - mx) + 1e-4f));
            u16 h2 = f2bf(0.0625f * (__expf(u[mf][nf][2] - dg - mx) + 1e-4f));
            u16 h3 = f2bf(0.0625f * (__expf(u[mf][nf][3] - dg - mx) + 1e-4f));
            uint2 w; w.x = (u32)h0 | ((u32)h1 << 16); w.y = (u32)h2 | ((u32)h3 << 16);
            const int mb = (wv * 64 + mf * 16 + (l >> 4) * 4) * 2;
            *(uint2*)((char*)qlds + s * 512 + (mb ^ ((s & 7) << 4))) = w;
        }
    }
    __syncthreads();
    f32x4 acc[2][2] = {};
    for (int kt = 0; kt < 8; ++kt) {
        short8 aq[2], bb[2];
#pragma unroll
        for (int mf = 0; mf < 2; ++mf) {
            const int s = mf * 16 + (l & 15);
            aq[mf] = *(const short8*)((const char*)qlds + s * 512 + ((kt * 64 + (l >> 4) * 16) ^ ((s & 7) << 4)));
        }
        {
            const int n0 = wv * 16 + (l & 15);
            bb[0] = *(const short8*)((const char*)Blds + n0 * 512 + ((kt * 64 + (l >> 4) * 16) ^ ((n0 & 7) << 4)));
            const int n1 = 64 + (l & 15);
            bb[1] = *(const short8*)((const char*)Blds + n1 * 512 + ((kt * 64 + (l >> 4) * 16) ^ ((n1 & 7) << 4)));
        }
#pragma unroll
        for (int mf = 0; mf < 2; ++mf)
#pragma unroll
            for (int nf = 0; nf < 2; ++nf)
                acc[mf][nf] = __builtin_amdgcn_mfma_f32_16x16x32_bf16(aq[mf], bb[nf], acc[mf][nf], 0, 0, 0);
    }
    const int b = bh >> 4, h = bh & 15;
#pragma unroll
    for (int mf = 0; mf < 2; ++mf) {
#pragma unroll
        for (int g = 0; g < 4; ++g) {
            const float den = __shfl(acc[mf][1][g], (l & 48));
            const float z = 1.0f / (den + 1e-6f);
            const int s = rt * 32 + mf * 16 + (l >> 4) * 4 + g;
            out[((size_t)b * SS + s) * DD + h * HDD + wv * 16 + (l & 15)] = acc[mf][0][g] * z;
        }
    }
}

// ---------------- launcher ----------------
extern "C" void kernel_launch(void* const* d_in, const int* in_sizes, int n_in,
                              void* d_out, int out_size, void* d_ws, size_t ws_size,
                              hipStream_t stream)
{
    const float* X    = (const float*)d_in[0];
    const float* mask = (const float*)d_in[1];
    const float* Wq   = (const float*)d_in[2];
    const float* bq   = (const float*)d_in[3];
    const float* Wk   = (const float*)d_in[4];
    const float* bk   = (const float*)d_in[5];
    const float* Wv   = (const float*)d_in[6];
    const float* bv   = (const float*)d_in[7];
    const float* proj = (const float*)d_in[8];
    float* out = (float*)d_out;

    char* p = (char*)d_ws;
    u16* Xbf = (u16*)p;                            // 32 MB (aliased by kv_part after gemm1)
    float* kv_part = (float*)p; p += 33554432;
    u16* Wt = (u16*)p;    p += 6291456;
    u16* projb = (u16*)p; p += 32768;
    u16* Qh = (u16*)p;    p += 33554432;
    u16* Kh = (u16*)p;    p += 33554432;
    u16* Vt = (u16*)p;    p += 33554432;
    float* dq = (float*)p; p += 1048576;
    float* dk = (float*)p; p += 1048576;
    u32* stabkey = (u32*)p; p += 256;
    float* ksum_part = (float*)p; p += 524288;
    u16* Bmat = (u16*)p;  p += 2621440;
    if (ws_size < 145785088ull) return;

    hipFuncSetAttribute((const void*)gemm1_big, hipFuncAttributeMaxDynamicSharedMemorySize, 131072);

    hipMemsetAsync(stabkey, 0, 256, stream);
    conv_bf16<<<16384, 256, 0, stream>>>(X, Xbf, 4194304);
    conv_w<<<dim3(48, 16), 256, 0, stream>>>(Wq, Wk, Wv, Wt);
    conv_bf16<<<16, 256, 0, stream>>>(proj, projb, 4096);
    gemm1_big<<<768, 512, 131072, stream>>>(Xbf, Wt, bq, bk, bv, mask, Qh, Kh, Vt, dq, dk);
    stab_kernel<<<dim3(64, 64), 256, 0, stream>>>(Kh, projb, stabkey);
    kv_fused<<<dim3(8, 64), 256, 0, stream>>>(Kh, Vt, projb, dk, stabkey, kv_part, ksum_part);
    reduceB2<<<dim3(64, 80), 256, 0, stream>>>(kv_part, ksum_part, Bmat);
    out_fused<<<dim3(128, 64), 256, 0, stream>>>(Qh, projb, dq, Bmat, out);
}